// Round 8
// baseline (671.641 us; speedup 1.0000x reference)
//
#include <hip/hip_runtime.h>
#include <hip/hip_fp16.h>
#include <math.h>

#define NN 100000
#define NE 1600000

#define BSH  7          // bucket shift: bucket = dst >> 7
#define BKN  128        // nodes per bucket
#define NBK  782        // ceil(NN/128)
#define ABLK 128        // partition blocks
#define EPB  ((NE + ABLK - 1) / ABLK)   // 12500 edges per partition block

typedef __attribute__((ext_vector_type(8))) short bf16x8;
typedef __attribute__((ext_vector_type(4))) float f32x4;

__device__ __forceinline__ unsigned short f2bf(float f) {
    unsigned u = __builtin_bit_cast(unsigned, f);
    u += 0x7fffu + ((u >> 16) & 1u);           // RNE
    return (unsigned short)(u >> 16);
}
__device__ __forceinline__ float bf2f(unsigned short h) {
    unsigned u = ((unsigned)h) << 16;
    return __builtin_bit_cast(float, u);
}
__device__ __forceinline__ float2 unpackh2(unsigned w) {
    const __half2 h = __builtin_bit_cast(__half2, w);
    return __half22float2(h);
}

// ---- A[128][64] = [w1l@w2l | w1l@w2r | w1r@w2l | w1r@w2r]
__global__ __launch_bounds__(64) void precomp_A(const float* __restrict__ w1l,
    const float* __restrict__ w1r, const float* __restrict__ w2l,
    const float* __restrict__ w2r, float* __restrict__ A)
{
    __shared__ float sl[64], sr[64];
    const int k = blockIdx.x;
    const int j = threadIdx.x;
    sl[j] = w1l[k * 64 + j];
    sr[j] = w1r[k * 64 + j];
    __syncthreads();
    const int sel = j >> 4, jj = j & 15;
    const float* row = (sel < 2) ? sl : sr;
    const float* w2  = (sel & 1) ? w2r : w2l;
    float acc = 0.f;
#pragma unroll
    for (int m = 0; m < 64; ++m) acc = fmaf(row[m], w2[m * 16 + jj], acc);
    A[k * 64 + j] = acc;
}

// ---- AT (transposed, bf16 hi/lo): ATh/ATl[col][k]
__global__ __launch_bounds__(256) void convA(const float* __restrict__ A,
    unsigned short* __restrict__ ATh, unsigned short* __restrict__ ATl)
{
    const int i = blockIdx.x * 256 + threadIdx.x;
    if (i >= 8192) return;
    const int col = i >> 7, k = i & 127;
    const float v = A[k * 64 + col];
    const unsigned short h = f2bf(v);
    ATh[col * 128 + k] = h;
    ATl[col * 128 + k] = f2bf(v - bf2f(h));
}

// ---- cbuf: [0:16)=b1@w2l  [16:32)=b1@w2r  [32:48)=v=fc1w@fc2w  [48]=c
__global__ void precomp_consts(const float* __restrict__ b1,
    const float* __restrict__ w2l, const float* __restrict__ w2r,
    const float* __restrict__ fc1w, const float* __restrict__ fc1b,
    const float* __restrict__ fc2w, const float* __restrict__ fc2b,
    float* __restrict__ cbuf)
{
    const int j = threadIdx.x;
    if (j < 16) {
        float a = 0.f;
        for (int m = 0; m < 64; ++m) a = fmaf(b1[m], w2l[m * 16 + j], a);
        cbuf[j] = a;
    } else if (j < 32) {
        const int jj = j - 16;
        float a = 0.f;
        for (int m = 0; m < 64; ++m) a = fmaf(b1[m], w2r[m * 16 + jj], a);
        cbuf[j] = a;
    } else if (j < 48) {
        const int k = j - 32;
        float a = 0.f;
        for (int m = 0; m < 8; ++m) a = fmaf(fc1w[k * 8 + m], fc2w[m], a);
        cbuf[j] = a;
    } else if (j == 48) {
        float a = fc2b[0];
        for (int m = 0; m < 8; ++m) a = fmaf(fc1b[m], fc2w[m], a);
        cbuf[48] = a;
    }
}

// ---- MFMA GEMM: y = x @ A (bf16 3-term split).
//      p (cols 0..31) -> int8 + per-row scale;  q (cols 32..63) -> fp16
#define LDST 136
__global__ __launch_bounds__(256) void gemm_mfma(const float* __restrict__ x,
    const unsigned short* __restrict__ ATh, const unsigned short* __restrict__ ATl,
    signed char* __restrict__ p8, float* __restrict__ pscale,
    __half* __restrict__ qh)
{
    __shared__ unsigned short sAh[64 * LDST];
    __shared__ unsigned short sAl[64 * LDST];
    const int tid = threadIdx.x;
    for (int i = tid; i < 1024; i += 256) {
        const int row = i >> 4, ch = i & 15;
        const uint4 vh = *(const uint4*)(ATh + row * 128 + ch * 8);
        const uint4 vl = *(const uint4*)(ATl + row * 128 + ch * 8);
        *(uint4*)(sAh + row * LDST + ch * 8) = vh;
        *(uint4*)(sAl + row * LDST + ch * 8) = vl;
    }
    __syncthreads();

    const int wave = tid >> 6;
    const int lane = tid & 63;
    const int lr = lane & 15;
    const int lg = lane >> 4;

    bf16x8 bh[4][4], bl[4][4];
#pragma unroll
    for (int ct = 0; ct < 4; ++ct) {
        const int col = ct * 16 + lr;
#pragma unroll
        for (int ks = 0; ks < 4; ++ks) {
            const int k0 = ks * 32 + lg * 8;
            bh[ct][ks] = *(const bf16x8*)(sAh + col * LDST + k0);
            bl[ct][ks] = *(const bf16x8*)(sAl + col * LDST + k0);
        }
    }

    const int tilebase = blockIdx.x * 64;
    const int xrowidx = tilebase + wave * 16 + lr;
    const float* xrow = x + (size_t)(xrowidx < NN ? xrowidx : NN - 1) * 128;

    f32x4 acc[4] = {f32x4{0,0,0,0}, f32x4{0,0,0,0}, f32x4{0,0,0,0}, f32x4{0,0,0,0}};
#pragma unroll
    for (int ks = 0; ks < 4; ++ks) {
        const int k0 = ks * 32 + lg * 8;
        const float4 v0 = *(const float4*)(xrow + k0);
        const float4 v1 = *(const float4*)(xrow + k0 + 4);
        const float vv[8] = {v0.x, v0.y, v0.z, v0.w, v1.x, v1.y, v1.z, v1.w};
        bf16x8 xh, xl;
#pragma unroll
        for (int j = 0; j < 8; ++j) {
            const unsigned short h = f2bf(vv[j]);
            xh[j] = (short)h;
            xl[j] = (short)f2bf(vv[j] - bf2f(h));
        }
#pragma unroll
        for (int ct = 0; ct < 4; ++ct) {
            acc[ct] = __builtin_amdgcn_mfma_f32_16x16x32_bf16(xh, bh[ct][ks], acc[ct], 0, 0, 0);
            acc[ct] = __builtin_amdgcn_mfma_f32_16x16x32_bf16(xh, bl[ct][ks], acc[ct], 0, 0, 0);
            acc[ct] = __builtin_amdgcn_mfma_f32_16x16x32_bf16(xl, bh[ct][ks], acc[ct], 0, 0, 0);
        }
    }

    // D layout: row = tilebase + wave*16 + lg*4 + rg; col = ct*16 + lr
#pragma unroll
    for (int rg = 0; rg < 4; ++rg) {
        float m = fmaxf(fabsf(acc[0][rg]), fabsf(acc[1][rg]));
#pragma unroll
        for (int d = 1; d < 16; d <<= 1) m = fmaxf(m, __shfl_xor(m, d, 64));
        m = fmaxf(m, 1e-20f);
        const float scl = m * (1.0f / 127.0f);
        const float inv = 127.0f / m;
        const int nrow = tilebase + wave * 16 + lg * 4 + rg;
        if (nrow < NN) {
            const int q0 = __float2int_rn(acc[0][rg] * inv);
            const int q1 = __float2int_rn(acc[1][rg] * inv);
            p8[(size_t)nrow * 32 + lr]      = (signed char)q0;
            p8[(size_t)nrow * 32 + 16 + lr] = (signed char)q1;
            if (lr == 0) pscale[nrow] = scl;
            qh[(size_t)nrow * 32 + lr]      = __float2half(acc[2][rg]);
            qh[(size_t)nrow * 32 + 16 + lr] = __float2half(acc[3][rg]);
        }
    }
}

// ============ bucket partition (two-level, write-combining friendly) ============
__global__ __launch_bounds__(256) void partA_count(const int* __restrict__ dst,
    int* __restrict__ mat)
{
    __shared__ int h[NBK];
    for (int i = threadIdx.x; i < NBK; i += 256) h[i] = 0;
    __syncthreads();
    const int a = blockIdx.x;
    const int beg = a * EPB;
    const int end = (beg + EPB < NE) ? beg + EPB : NE;
    for (int e = beg + threadIdx.x; e < end; e += 256)
        atomicAdd(&h[dst[e] >> BSH], 1);
    __syncthreads();
    for (int i = threadIdx.x; i < NBK; i += 256) mat[a * NBK + i] = h[i];
}

__global__ __launch_bounds__(256) void partA_scan(int* __restrict__ mat,
    int* __restrict__ bbase)
{
    __shared__ int tot[NBK];
    for (int b = threadIdx.x; b < NBK; b += 256) {
        int run = 0;
        for (int a = 0; a < ABLK; ++a) {
            const int t = mat[a * NBK + b];
            mat[a * NBK + b] = run;
            run += t;
        }
        tot[b] = run;
    }
    __syncthreads();
    if (threadIdx.x == 0) {
        int acc = 0;
        for (int i = 0; i < NBK; ++i) {
            const int t = tot[i];
            tot[i] = acc;
            bbase[i] = acc;
            acc += t;
        }
        bbase[NBK] = acc;   // == NE
    }
    __syncthreads();
    for (int b = threadIdx.x; b < NBK; b += 256) {
        const int base = tot[b];
        for (int a = 0; a < ABLK; ++a) mat[a * NBK + b] += base;
    }
}

// packed entry: (src << 7) | local_dst   (src < 2^17, local < 128)
__global__ __launch_bounds__(256) void partA_scatter(const int* __restrict__ src,
    const int* __restrict__ dst, const int* __restrict__ mat,
    unsigned* __restrict__ part)
{
    __shared__ int cur[NBK];
    const int a = blockIdx.x;
    for (int i = threadIdx.x; i < NBK; i += 256) cur[i] = mat[a * NBK + i];
    __syncthreads();
    const int beg = a * EPB;
    const int end = (beg + EPB < NE) ? beg + EPB : NE;
    for (int e = beg + threadIdx.x; e < end; e += 256) {
        const int s = src[e], d = dst[e];
        const int pos = atomicAdd(&cur[d >> BSH], 1);
        part[pos] = ((unsigned)s << BSH) | (unsigned)(d & (BKN - 1));
    }
}

// ============ bucketed aggregation: stream part, LDS accumulate ============
// layer 1: gather p8 (int8, per-row scale) -> LDS accum [128][32] -> g,r (fp16)
__global__ __launch_bounds__(512) void agg1_b(const unsigned* __restrict__ part,
    const int* __restrict__ bbase, const signed char* __restrict__ p8,
    const float* __restrict__ pscale, const __half* __restrict__ qh,
    const float* __restrict__ cbuf, __half* __restrict__ g, __half* __restrict__ r)
{
    __shared__ float acc[BKN * 32];   // 16 KB
    __shared__ int cnt[BKN];
    const int b = blockIdx.x;
    const int nbase = b << BSH;
    for (int i = threadIdx.x; i < BKN * 32; i += 512) acc[i] = 0.f;
    for (int i = threadIdx.x; i < BKN; i += 512) cnt[i] = 0;
    __syncthreads();

    const int beg = bbase[b], end = bbase[b + 1];
    const int gi = threadIdx.x >> 5;   // 16 groups of 32 lanes
    const int f  = threadIdx.x & 31;
    int e = beg + gi;
    for (; e + 16 < end; e += 32) {
        const unsigned w0 = part[e];
        const unsigned w1 = part[e + 16];
        const int s0 = (int)(w0 >> BSH), l0 = (int)(w0 & (BKN - 1));
        const int s1 = (int)(w1 >> BSH), l1 = (int)(w1 & (BKN - 1));
        const float v0 = (float)p8[(size_t)s0 * 32 + f] * pscale[s0];
        const float v1 = (float)p8[(size_t)s1 * 32 + f] * pscale[s1];
        atomicAdd(&acc[l0 * 32 + f], v0);
        atomicAdd(&acc[l1 * 32 + f], v1);
        if (f == 0) { atomicAdd(&cnt[l0], 1); atomicAdd(&cnt[l1], 1); }
    }
    if (e < end) {
        const unsigned w = part[e];
        const int s = (int)(w >> BSH), l = (int)(w & (BKN - 1));
        const float v = (float)p8[(size_t)s * 32 + f] * pscale[s];
        atomicAdd(&acc[l * 32 + f], v);
        if (f == 0) atomicAdd(&cnt[l], 1);
    }
    __syncthreads();

    for (int i = threadIdx.x; i < BKN * 32; i += 512) {
        const int ln = i >> 5, ff = i & 31;
        const int node = nbase + ln;
        if (node >= NN) continue;
        const float dg = (float)cnt[ln];
        const float m = acc[i] * (1.0f / fmaxf(dg, 1.0f));
        const float val = m + __half2float(qh[(size_t)node * 32 + ff]) + cbuf[ff];
        if (ff < 16) g[(size_t)node * 16 + ff] = __float2half(val);
        else         r[(size_t)node * 16 + (ff - 16)] = __float2half(val);
    }
}

// layer 2: gather g (fp16) -> LDS accum [128][16] -> h2 (fp16)
__global__ __launch_bounds__(512) void agg2_b(const unsigned* __restrict__ part,
    const int* __restrict__ bbase, const __half* __restrict__ g,
    const __half* __restrict__ r, const float* __restrict__ b2,
    __half* __restrict__ h2)
{
    __shared__ float acc[BKN * 16];   // 8 KB
    __shared__ int cnt[BKN];
    const int b = blockIdx.x;
    const int nbase = b << BSH;
    for (int i = threadIdx.x; i < BKN * 16; i += 512) acc[i] = 0.f;
    for (int i = threadIdx.x; i < BKN; i += 512) cnt[i] = 0;
    __syncthreads();

    const int beg = bbase[b], end = bbase[b + 1];
    const int gi = threadIdx.x >> 4;   // 32 groups of 16 lanes
    const int f  = threadIdx.x & 15;
    int e = beg + gi;
    for (; e + 32 < end; e += 64) {
        const unsigned w0 = part[e];
        const unsigned w1 = part[e + 32];
        const int s0 = (int)(w0 >> BSH), l0 = (int)(w0 & (BKN - 1));
        const int s1 = (int)(w1 >> BSH), l1 = (int)(w1 & (BKN - 1));
        const float v0 = __half2float(g[(size_t)s0 * 16 + f]);
        const float v1 = __half2float(g[(size_t)s1 * 16 + f]);
        atomicAdd(&acc[l0 * 16 + f], v0);
        atomicAdd(&acc[l1 * 16 + f], v1);
        if (f == 0) { atomicAdd(&cnt[l0], 1); atomicAdd(&cnt[l1], 1); }
    }
    if (e < end) {
        const unsigned w = part[e];
        const int s = (int)(w >> BSH), l = (int)(w & (BKN - 1));
        const float v = __half2float(g[(size_t)s * 16 + f]);
        atomicAdd(&acc[l * 16 + f], v);
        if (f == 0) atomicAdd(&cnt[l], 1);
    }
    __syncthreads();

    for (int i = threadIdx.x; i < BKN * 16; i += 512) {
        const int ln = i >> 4, ff = i & 15;
        const int node = nbase + ln;
        if (node >= NN) continue;
        const float dg = (float)cnt[ln];
        const float val = acc[i] * (1.0f / fmaxf(dg, 1.0f))
                        + __half2float(r[(size_t)node * 16 + ff]) + b2[ff];
        h2[(size_t)node * 16 + ff] = __float2half(val);
    }
}

// ---- out = sigmoid( sum_k h2[s][k]*h2[d][k]*v[k] + c )
__global__ __launch_bounds__(256) void edge_mlp(const int* __restrict__ src,
    const int* __restrict__ dst, const __half* __restrict__ h2,
    const float* __restrict__ cbuf, float* __restrict__ out)
{
    __shared__ float sv[17];
    if (threadIdx.x < 16) sv[threadIdx.x] = cbuf[32 + threadIdx.x];
    if (threadIdx.x == 16) sv[16] = cbuf[48];
    __syncthreads();
    const int e = blockIdx.x * 256 + threadIdx.x;
    if (e >= NE) return;
    const int s = src[e], d = dst[e];
    const uint4* hs = (const uint4*)(h2 + (size_t)s * 16);
    const uint4* hd = (const uint4*)(h2 + (size_t)d * 16);
    float acc = sv[16];
    const uint4 a0 = hs[0], a1 = hs[1];
    const uint4 b0 = hd[0], b1 = hd[1];
    const unsigned aw[8] = {a0.x, a0.y, a0.z, a0.w, a1.x, a1.y, a1.z, a1.w};
    const unsigned bw[8] = {b0.x, b0.y, b0.z, b0.w, b1.x, b1.y, b1.z, b1.w};
#pragma unroll
    for (int qq = 0; qq < 8; ++qq) {
        const float2 a = unpackh2(aw[qq]);
        const float2 b = unpackh2(bw[qq]);
        acc = fmaf(a.x * b.x, sv[qq * 2 + 0], acc);
        acc = fmaf(a.y * b.y, sv[qq * 2 + 1], acc);
    }
    out[e] = 1.0f / (1.0f + __expf(-acc));
}

extern "C" void kernel_launch(void* const* d_in, const int* in_sizes, int n_in,
                              void* d_out, int out_size, void* d_ws, size_t ws_size,
                              hipStream_t stream)
{
    const float* x    = (const float*)d_in[0];
    const int*   ei   = (const int*)d_in[1];
    const float* w1l  = (const float*)d_in[2];
    const float* w1r  = (const float*)d_in[3];
    const float* b1   = (const float*)d_in[4];
    const float* w2l  = (const float*)d_in[5];
    const float* w2r  = (const float*)d_in[6];
    const float* b2   = (const float*)d_in[7];
    const float* fc1w = (const float*)d_in[8];
    const float* fc1b = (const float*)d_in[9];
    const float* fc2w = (const float*)d_in[10];
    const float* fc2b = (const float*)d_in[11];
    float* out = (float*)d_out;

    const int* src = ei;
    const int* dst = ei + NE;

    // workspace layout (int units)
    int* W = (int*)d_ws;
    size_t o = 0;
#define ALIGN16() o = (o + 15) & ~(size_t)15
    int* mat    = W + o; o += (size_t)ABLK * NBK; ALIGN16();
    int* bbase  = W + o; o += NBK + 1;           ALIGN16();
    unsigned* part = (unsigned*)(W + o); o += NE; ALIGN16();
    float* A    = (float*)(W + o); o += 8192;    ALIGN16();
    unsigned short* ATh = (unsigned short*)(W + o); o += 4096; ALIGN16();
    unsigned short* ATl = (unsigned short*)(W + o); o += 4096; ALIGN16();
    float* cbuf = (float*)(W + o); o += 64;      ALIGN16();
    signed char* p8 = (signed char*)(W + o); o += (size_t)NN * 8;  ALIGN16();
    float* pscale   = (float*)(W + o); o += NN;  ALIGN16();
    __half* qh  = (__half*)(W + o); o += (size_t)NN * 16; ALIGN16();
    __half* g   = (__half*)(W + o); o += (size_t)NN * 8;  ALIGN16();
    __half* r   = (__half*)(W + o); o += (size_t)NN * 8;  ALIGN16();
    __half* h2  = (__half*)(W + o); o += (size_t)NN * 8;  ALIGN16();

    precomp_A<<<128, 64, 0, stream>>>(w1l, w1r, w2l, w2r, A);
    convA<<<32, 256, 0, stream>>>(A, ATh, ATl);
    precomp_consts<<<1, 64, 0, stream>>>(b1, w2l, w2r, fc1w, fc1b, fc2w, fc2b, cbuf);

    // bucket partition
    partA_count<<<ABLK, 256, 0, stream>>>(dst, mat);
    partA_scan<<<1, 256, 0, stream>>>(mat, bbase);
    partA_scatter<<<ABLK, 256, 0, stream>>>(src, dst, mat, part);

    // dense projection (MFMA, int8 payload epilogue)
    gemm_mfma<<<(NN + 63) / 64, 256, 0, stream>>>(x, ATh, ATl, p8, pscale, qh);

    // bucketed aggregations (LDS accumulate, no fp global atomics, no CSR)
    agg1_b<<<NBK, 512, 0, stream>>>(part, bbase, p8, pscale, qh, cbuf, g, r);
    agg2_b<<<NBK, 512, 0, stream>>>(part, bbase, g, r, b2, h2);

    // head
    edge_mlp<<<NE / 256, 256, 0, stream>>>(src, dst, h2, cbuf, out);
}

// Round 9
// 210.795 us; speedup vs baseline: 3.1862x; 3.1862x over previous
//
#include <hip/hip_runtime.h>
#include <hip/hip_fp16.h>
#include <math.h>

#define NN 100000
#define NE 1600000

#define BSH  9          // bucket = dst >> 9
#define BKN  512        // nodes per bucket
#define NB   196        // ceil(NN/512)
#define ABLK 128        // partition blocks
#define EPB  ((NE + ABLK - 1) / ABLK)   // 12500 edges per partition block

typedef __attribute__((ext_vector_type(8))) short bf16x8;
typedef __attribute__((ext_vector_type(4))) float f32x4;

__device__ __forceinline__ unsigned short f2bf(float f) {
    unsigned u = __builtin_bit_cast(unsigned, f);
    u += 0x7fffu + ((u >> 16) & 1u);           // RNE
    return (unsigned short)(u >> 16);
}
__device__ __forceinline__ float bf2f(unsigned short h) {
    unsigned u = ((unsigned)h) << 16;
    return __builtin_bit_cast(float, u);
}
__device__ __forceinline__ float2 unpackh2(unsigned w) {
    const __half2 h = __builtin_bit_cast(__half2, w);
    return __half22float2(h);
}

// ---- A[128][64] = [w1l@w2l | w1l@w2r | w1r@w2l | w1r@w2r]
__global__ __launch_bounds__(64) void precomp_A(const float* __restrict__ w1l,
    const float* __restrict__ w1r, const float* __restrict__ w2l,
    const float* __restrict__ w2r, float* __restrict__ A)
{
    __shared__ float sl[64], sr[64];
    const int k = blockIdx.x;
    const int j = threadIdx.x;
    sl[j] = w1l[k * 64 + j];
    sr[j] = w1r[k * 64 + j];
    __syncthreads();
    const int sel = j >> 4, jj = j & 15;
    const float* row = (sel < 2) ? sl : sr;
    const float* w2  = (sel & 1) ? w2r : w2l;
    float acc = 0.f;
#pragma unroll
    for (int m = 0; m < 64; ++m) acc = fmaf(row[m], w2[m * 16 + jj], acc);
    A[k * 64 + j] = acc;
}

// ---- AT (transposed, bf16 hi/lo): ATh/ATl[col][k]
__global__ __launch_bounds__(256) void convA(const float* __restrict__ A,
    unsigned short* __restrict__ ATh, unsigned short* __restrict__ ATl)
{
    const int i = blockIdx.x * 256 + threadIdx.x;
    if (i >= 8192) return;
    const int col = i >> 7, k = i & 127;
    const float v = A[k * 64 + col];
    const unsigned short h = f2bf(v);
    ATh[col * 128 + k] = h;
    ATl[col * 128 + k] = f2bf(v - bf2f(h));
}

// ---- cbuf: [0:16)=b1@w2l  [16:32)=b1@w2r  [32:48)=v=fc1w@fc2w  [48]=c
__global__ void precomp_consts(const float* __restrict__ b1,
    const float* __restrict__ w2l, const float* __restrict__ w2r,
    const float* __restrict__ fc1w, const float* __restrict__ fc1b,
    const float* __restrict__ fc2w, const float* __restrict__ fc2b,
    float* __restrict__ cbuf)
{
    const int j = threadIdx.x;
    if (j < 16) {
        float a = 0.f;
        for (int m = 0; m < 64; ++m) a = fmaf(b1[m], w2l[m * 16 + j], a);
        cbuf[j] = a;
    } else if (j < 32) {
        const int jj = j - 16;
        float a = 0.f;
        for (int m = 0; m < 64; ++m) a = fmaf(b1[m], w2r[m * 16 + jj], a);
        cbuf[j] = a;
    } else if (j < 48) {
        const int k = j - 32;
        float a = 0.f;
        for (int m = 0; m < 8; ++m) a = fmaf(fc1w[k * 8 + m], fc2w[m], a);
        cbuf[j] = a;
    } else if (j == 48) {
        float a = fc2b[0];
        for (int m = 0; m < 8; ++m) a = fmaf(fc1b[m], fc2w[m], a);
        cbuf[48] = a;
    }
}

// ---- MFMA GEMM: y = x @ A (bf16 3-term split).
//      p (cols 0..31) -> int8 + per-row scale;  q (cols 32..63) -> fp16
#define LDST 136
__global__ __launch_bounds__(256) void gemm_mfma(const float* __restrict__ x,
    const unsigned short* __restrict__ ATh, const unsigned short* __restrict__ ATl,
    signed char* __restrict__ p8, float* __restrict__ pscale,
    __half* __restrict__ qh)
{
    __shared__ unsigned short sAh[64 * LDST];
    __shared__ unsigned short sAl[64 * LDST];
    const int tid = threadIdx.x;
    for (int i = tid; i < 1024; i += 256) {
        const int row = i >> 4, ch = i & 15;
        const uint4 vh = *(const uint4*)(ATh + row * 128 + ch * 8);
        const uint4 vl = *(const uint4*)(ATl + row * 128 + ch * 8);
        *(uint4*)(sAh + row * LDST + ch * 8) = vh;
        *(uint4*)(sAl + row * LDST + ch * 8) = vl;
    }
    __syncthreads();

    const int wave = tid >> 6;
    const int lane = tid & 63;
    const int lr = lane & 15;
    const int lg = lane >> 4;

    bf16x8 bh[4][4], bl[4][4];
#pragma unroll
    for (int ct = 0; ct < 4; ++ct) {
        const int col = ct * 16 + lr;
#pragma unroll
        for (int ks = 0; ks < 4; ++ks) {
            const int k0 = ks * 32 + lg * 8;
            bh[ct][ks] = *(const bf16x8*)(sAh + col * LDST + k0);
            bl[ct][ks] = *(const bf16x8*)(sAl + col * LDST + k0);
        }
    }

    const int tilebase = blockIdx.x * 64;
    const int xrowidx = tilebase + wave * 16 + lr;
    const float* xrow = x + (size_t)(xrowidx < NN ? xrowidx : NN - 1) * 128;

    f32x4 acc[4] = {f32x4{0,0,0,0}, f32x4{0,0,0,0}, f32x4{0,0,0,0}, f32x4{0,0,0,0}};
#pragma unroll
    for (int ks = 0; ks < 4; ++ks) {
        const int k0 = ks * 32 + lg * 8;
        const float4 v0 = *(const float4*)(xrow + k0);
        const float4 v1 = *(const float4*)(xrow + k0 + 4);
        const float vv[8] = {v0.x, v0.y, v0.z, v0.w, v1.x, v1.y, v1.z, v1.w};
        bf16x8 xh, xl;
#pragma unroll
        for (int j = 0; j < 8; ++j) {
            const unsigned short h = f2bf(vv[j]);
            xh[j] = (short)h;
            xl[j] = (short)f2bf(vv[j] - bf2f(h));
        }
#pragma unroll
        for (int ct = 0; ct < 4; ++ct) {
            acc[ct] = __builtin_amdgcn_mfma_f32_16x16x32_bf16(xh, bh[ct][ks], acc[ct], 0, 0, 0);
            acc[ct] = __builtin_amdgcn_mfma_f32_16x16x32_bf16(xh, bl[ct][ks], acc[ct], 0, 0, 0);
            acc[ct] = __builtin_amdgcn_mfma_f32_16x16x32_bf16(xl, bh[ct][ks], acc[ct], 0, 0, 0);
        }
    }

    // D layout: row = tilebase + wave*16 + lg*4 + rg; col = ct*16 + lr
#pragma unroll
    for (int rg = 0; rg < 4; ++rg) {
        float m = fmaxf(fabsf(acc[0][rg]), fabsf(acc[1][rg]));
#pragma unroll
        for (int d = 1; d < 16; d <<= 1) m = fmaxf(m, __shfl_xor(m, d, 64));
        m = fmaxf(m, 1e-20f);
        const float scl = m * (1.0f / 127.0f);
        const float inv = 127.0f / m;
        const int nrow = tilebase + wave * 16 + lg * 4 + rg;
        if (nrow < NN) {
            const int q0 = __float2int_rn(acc[0][rg] * inv);
            const int q1 = __float2int_rn(acc[1][rg] * inv);
            p8[(size_t)nrow * 32 + lr]      = (signed char)q0;
            p8[(size_t)nrow * 32 + 16 + lr] = (signed char)q1;
            if (lr == 0) pscale[nrow] = scl;
            qh[(size_t)nrow * 32 + lr]      = __float2half(acc[2][rg]);
            qh[(size_t)nrow * 32 + 16 + lr] = __float2half(acc[3][rg]);
        }
    }
}

// ============ bucketed CSR build ============
// mat layout: [bucket][ablock]  (contiguous per-bucket for parallel scan)
__global__ __launch_bounds__(256) void partA_count(const int* __restrict__ dst,
    int* __restrict__ mat)
{
    __shared__ int h[NB];
    for (int i = threadIdx.x; i < NB; i += 256) h[i] = 0;
    __syncthreads();
    const int a = blockIdx.x;
    const int beg = a * EPB;
    const int end = (beg + EPB < NE) ? beg + EPB : NE;
    for (int e = beg + threadIdx.x; e < end; e += 256)
        atomicAdd(&h[dst[e] >> BSH], 1);
    __syncthreads();
    for (int i = threadIdx.x; i < NB; i += 256) mat[(size_t)i * ABLK + a] = h[i];
}

// per-bucket prefix over the 128 partition blocks (one thread per bucket)
__global__ __launch_bounds__(256) void scan_cols(int* __restrict__ mat,
    int* __restrict__ tot)
{
    const int b = blockIdx.x * 256 + threadIdx.x;
    if (b >= NB) return;
    int* col = mat + (size_t)b * ABLK;
    int run = 0;
    for (int a = 0; a < ABLK; ++a) { const int t = col[a]; col[a] = run; run += t; }
    tot[b] = run;
}

__global__ void scan_tot(const int* __restrict__ tot, int* __restrict__ bbase)
{
    if (threadIdx.x == 0) {
        int acc = 0;
        for (int i = 0; i < NB; ++i) { bbase[i] = acc; acc += tot[i]; }
        bbase[NB] = acc;   // == NE
    }
}

// packed entry: (src << BSH) | local_dst
__global__ __launch_bounds__(256) void partA_scatter(const int* __restrict__ src,
    const int* __restrict__ dst, const int* __restrict__ mat,
    const int* __restrict__ bbase, unsigned* __restrict__ part)
{
    __shared__ int cur[NB];
    const int a = blockIdx.x;
    for (int i = threadIdx.x; i < NB; i += 256)
        cur[i] = mat[(size_t)i * ABLK + a] + bbase[i];
    __syncthreads();
    const int beg = a * EPB;
    const int end = (beg + EPB < NE) ? beg + EPB : NE;
    for (int e = beg + threadIdx.x; e < end; e += 256) {
        const int s = src[e], d = dst[e];
        const int pos = atomicAdd(&cur[d >> BSH], 1);
        part[pos] = ((unsigned)s << BSH) | (unsigned)(d & (BKN - 1));
    }
}

__global__ __launch_bounds__(512) void partB_build(const unsigned* __restrict__ part,
    const int* __restrict__ bbase, int* __restrict__ rowptr, int* __restrict__ cols)
{
    __shared__ int h[BKN];
    __shared__ int cur[BKN];
    const int b = blockIdx.x;
    const int beg = bbase[b], end = bbase[b + 1];
    h[threadIdx.x] = 0;
    __syncthreads();
    for (int e = beg + threadIdx.x; e < end; e += 512)
        atomicAdd(&h[part[e] & (BKN - 1u)], 1);
    __syncthreads();
    const int v = h[threadIdx.x];
    for (int off = 1; off < BKN; off <<= 1) {
        const int t = (threadIdx.x >= off) ? h[threadIdx.x - off] : 0;
        __syncthreads();
        h[threadIdx.x] += t;
        __syncthreads();
    }
    const int excl = h[threadIdx.x] - v;
    cur[threadIdx.x] = excl;
    const int node = b * BKN + threadIdx.x;
    if (node < NN) rowptr[node] = beg + excl;
    if (b == NB - 1 && threadIdx.x == 0) rowptr[NN] = NE;
    __syncthreads();
    for (int e = beg + threadIdx.x; e < end; e += 512) {
        const unsigned w = part[e];
        const int pos = atomicAdd(&cur[w & (BKN - 1u)], 1);
        cols[beg + pos] = (int)(w >> BSH);
    }
}

// ============ aggregation via CSR ============
// layer 1: one 64-lane wave per node; 2 edge-halves x 4-unroll = 8 gathers in flight
__global__ __launch_bounds__(256) void agg1_csr(const int* __restrict__ rowptr,
    const int* __restrict__ cols, const signed char* __restrict__ p8,
    const float* __restrict__ pscale, const __half* __restrict__ qh,
    const float* __restrict__ cbuf, __half* __restrict__ g, __half* __restrict__ r)
{
    const int node = blockIdx.x * 4 + (threadIdx.x >> 6);
    if (node >= NN) return;
    const int lane = threadIdx.x & 63;
    const int f = lane & 31;
    const int h = lane >> 5;       // 0 or 1
    const int beg = rowptr[node], end = rowptr[node + 1];
    float acc = 0.f;
    int j = beg + h;
    for (; j + 6 < end; j += 8) {
        const int s0 = cols[j], s1 = cols[j + 2], s2 = cols[j + 4], s3 = cols[j + 6];
        const float v0 = (float)p8[(size_t)s0 * 32 + f] * pscale[s0];
        const float v1 = (float)p8[(size_t)s1 * 32 + f] * pscale[s1];
        const float v2 = (float)p8[(size_t)s2 * 32 + f] * pscale[s2];
        const float v3 = (float)p8[(size_t)s3 * 32 + f] * pscale[s3];
        acc += (v0 + v1) + (v2 + v3);
    }
    for (; j < end; j += 2) {
        const int s = cols[j];
        acc += (float)p8[(size_t)s * 32 + f] * pscale[s];
    }
    acc += __shfl_xor(acc, 32, 64);
    if (lane < 32) {
        const float dg = (float)(end - beg);
        const float m = acc * (1.0f / fmaxf(dg, 1.0f));
        const float val = m + __half2float(qh[(size_t)node * 32 + f]) + cbuf[f];
        if (f < 16) g[(size_t)node * 16 + f] = __float2half(val);
        else        r[(size_t)node * 16 + (f - 16)] = __float2half(val);
    }
}

// layer 2: one wave per node; 4 edge-slots x 2-unroll = 8 gathers in flight
__global__ __launch_bounds__(256) void agg2_csr(const int* __restrict__ rowptr,
    const int* __restrict__ cols, const __half* __restrict__ g,
    const __half* __restrict__ r, const float* __restrict__ b2,
    __half* __restrict__ h2)
{
    const int node = blockIdx.x * 4 + (threadIdx.x >> 6);
    if (node >= NN) return;
    const int lane = threadIdx.x & 63;
    const int f = lane & 15;
    const int h = lane >> 4;       // 0..3
    const int beg = rowptr[node], end = rowptr[node + 1];
    float acc = 0.f;
    int j = beg + h;
    for (; j + 4 < end; j += 8) {
        const int s0 = cols[j], s1 = cols[j + 4];
        acc += __half2float(g[(size_t)s0 * 16 + f]) + __half2float(g[(size_t)s1 * 16 + f]);
    }
    for (; j < end; j += 4)
        acc += __half2float(g[(size_t)cols[j] * 16 + f]);
    acc += __shfl_xor(acc, 16, 64);
    acc += __shfl_xor(acc, 32, 64);
    if (lane < 16) {
        const float dg = (float)(end - beg);
        const float val = acc * (1.0f / fmaxf(dg, 1.0f))
                        + __half2float(r[(size_t)node * 16 + f]) + b2[f];
        h2[(size_t)node * 16 + f] = __float2half(val);
    }
}

// ---- out = sigmoid( sum_k h2[s][k]*h2[d][k]*v[k] + c )
__global__ __launch_bounds__(256) void edge_mlp(const int* __restrict__ src,
    const int* __restrict__ dst, const __half* __restrict__ h2,
    const float* __restrict__ cbuf, float* __restrict__ out)
{
    __shared__ float sv[17];
    if (threadIdx.x < 16) sv[threadIdx.x] = cbuf[32 + threadIdx.x];
    if (threadIdx.x == 16) sv[16] = cbuf[48];
    __syncthreads();
    const int e = blockIdx.x * 256 + threadIdx.x;
    if (e >= NE) return;
    const int s = src[e], d = dst[e];
    const uint4* hs = (const uint4*)(h2 + (size_t)s * 16);
    const uint4* hd = (const uint4*)(h2 + (size_t)d * 16);
    float acc = sv[16];
    const uint4 a0 = hs[0], a1 = hs[1];
    const uint4 b0 = hd[0], b1 = hd[1];
    const unsigned aw[8] = {a0.x, a0.y, a0.z, a0.w, a1.x, a1.y, a1.z, a1.w};
    const unsigned bw[8] = {b0.x, b0.y, b0.z, b0.w, b1.x, b1.y, b1.z, b1.w};
#pragma unroll
    for (int qq = 0; qq < 8; ++qq) {
        const float2 a = unpackh2(aw[qq]);
        const float2 b = unpackh2(bw[qq]);
        acc = fmaf(a.x * b.x, sv[qq * 2 + 0], acc);
        acc = fmaf(a.y * b.y, sv[qq * 2 + 1], acc);
    }
    out[e] = 1.0f / (1.0f + __expf(-acc));
}

extern "C" void kernel_launch(void* const* d_in, const int* in_sizes, int n_in,
                              void* d_out, int out_size, void* d_ws, size_t ws_size,
                              hipStream_t stream)
{
    const float* x    = (const float*)d_in[0];
    const int*   ei   = (const int*)d_in[1];
    const float* w1l  = (const float*)d_in[2];
    const float* w1r  = (const float*)d_in[3];
    const float* b1   = (const float*)d_in[4];
    const float* w2l  = (const float*)d_in[5];
    const float* w2r  = (const float*)d_in[6];
    const float* b2   = (const float*)d_in[7];
    const float* fc1w = (const float*)d_in[8];
    const float* fc1b = (const float*)d_in[9];
    const float* fc2w = (const float*)d_in[10];
    const float* fc2b = (const float*)d_in[11];
    float* out = (float*)d_out;

    const int* src = ei;
    const int* dst = ei + NE;

    // workspace layout (int units)
    int* W = (int*)d_ws;
    size_t o = 0;
#define ALIGN16() o = (o + 15) & ~(size_t)15
    int* mat    = W + o; o += (size_t)NB * ABLK; ALIGN16();
    int* tot    = W + o; o += NB;                ALIGN16();
    int* bbase  = W + o; o += NB + 1;            ALIGN16();
    int* rowptr = W + o; o += NN + 1;            ALIGN16();
    unsigned* part = (unsigned*)(W + o); o += NE; ALIGN16();
    int* cols   = W + o; o += NE;                ALIGN16();
    float* A    = (float*)(W + o); o += 8192;    ALIGN16();
    unsigned short* ATh = (unsigned short*)(W + o); o += 4096; ALIGN16();
    unsigned short* ATl = (unsigned short*)(W + o); o += 4096; ALIGN16();
    float* cbuf = (float*)(W + o); o += 64;      ALIGN16();
    signed char* p8 = (signed char*)(W + o); o += (size_t)NN * 8;  ALIGN16();
    float* pscale   = (float*)(W + o); o += NN;  ALIGN16();
    __half* qh  = (__half*)(W + o); o += (size_t)NN * 16; ALIGN16();
    __half* g   = (__half*)(W + o); o += (size_t)NN * 8;  ALIGN16();
    __half* r   = (__half*)(W + o); o += (size_t)NN * 8;  ALIGN16();
    __half* h2  = (__half*)(W + o); o += (size_t)NN * 8;  ALIGN16();

    precomp_A<<<128, 64, 0, stream>>>(w1l, w1r, w2l, w2r, A);
    convA<<<32, 256, 0, stream>>>(A, ATh, ATl);
    precomp_consts<<<1, 64, 0, stream>>>(b1, w2l, w2r, fc1w, fc1b, fc2w, fc2b, cbuf);

    // bucketed CSR build (parallel scan)
    partA_count<<<ABLK, 256, 0, stream>>>(dst, mat);
    scan_cols<<<(NB + 255) / 256, 256, 0, stream>>>(mat, tot);
    scan_tot<<<1, 64, 0, stream>>>(tot, bbase);
    partA_scatter<<<ABLK, 256, 0, stream>>>(src, dst, mat, bbase, part);
    partB_build<<<NB, 512, 0, stream>>>(part, bbase, rowptr, cols);

    // dense projection (MFMA, int8 payload epilogue)
    gemm_mfma<<<(NN + 63) / 64, 256, 0, stream>>>(x, ATh, ATl, p8, pscale, qh);

    // aggregations (gather, wave-per-node, 8 loads in flight)
    agg1_csr<<<(NN + 3) / 4, 256, 0, stream>>>(rowptr, cols, p8, pscale, qh, cbuf, g, r);
    agg2_csr<<<(NN + 3) / 4, 256, 0, stream>>>(rowptr, cols, g, r, b2, h2);

    // head
    edge_mlp<<<NE / 256, 256, 0, stream>>>(src, dst, h2, cbuf, out);
}

// Round 10
// 176.912 us; speedup vs baseline: 3.7965x; 1.1915x over previous
//
#include <hip/hip_runtime.h>
#include <hip/hip_fp16.h>
#include <math.h>

#define NN 100000
#define NE 1600000

#define BSH  9          // bucket = dst >> 9
#define BKN  512        // nodes per bucket
#define NB   196        // ceil(NN/512)
#define ABLK 128        // partition blocks
#define EPB  ((NE + ABLK - 1) / ABLK)   // 12500 edges per partition block

typedef __attribute__((ext_vector_type(8))) short bf16x8;
typedef __attribute__((ext_vector_type(4))) float f32x4;

__device__ __forceinline__ unsigned short f2bf(float f) {
    unsigned u = __builtin_bit_cast(unsigned, f);
    u += 0x7fffu + ((u >> 16) & 1u);           // RNE
    return (unsigned short)(u >> 16);
}
__device__ __forceinline__ float bf2f(unsigned short h) {
    unsigned u = ((unsigned)h) << 16;
    return __builtin_bit_cast(float, u);
}
__device__ __forceinline__ float2 unpackh2(unsigned w) {
    const __half2 h = __builtin_bit_cast(__half2, w);
    return __half22float2(h);
}

// ---- A[128][64] = [w1l@w2l | w1l@w2r | w1r@w2l | w1r@w2r]
__global__ __launch_bounds__(64) void precomp_A(const float* __restrict__ w1l,
    const float* __restrict__ w1r, const float* __restrict__ w2l,
    const float* __restrict__ w2r, float* __restrict__ A)
{
    __shared__ float sl[64], sr[64];
    const int k = blockIdx.x;
    const int j = threadIdx.x;
    sl[j] = w1l[k * 64 + j];
    sr[j] = w1r[k * 64 + j];
    __syncthreads();
    const int sel = j >> 4, jj = j & 15;
    const float* row = (sel < 2) ? sl : sr;
    const float* w2  = (sel & 1) ? w2r : w2l;
    float acc = 0.f;
#pragma unroll
    for (int m = 0; m < 64; ++m) acc = fmaf(row[m], w2[m * 16 + jj], acc);
    A[k * 64 + j] = acc;
}

// ---- AT (transposed, bf16 hi/lo): ATh/ATl[col][k]
__global__ __launch_bounds__(256) void convA(const float* __restrict__ A,
    unsigned short* __restrict__ ATh, unsigned short* __restrict__ ATl)
{
    const int i = blockIdx.x * 256 + threadIdx.x;
    if (i >= 8192) return;
    const int col = i >> 7, k = i & 127;
    const float v = A[k * 64 + col];
    const unsigned short h = f2bf(v);
    ATh[col * 128 + k] = h;
    ATl[col * 128 + k] = f2bf(v - bf2f(h));
}

// ---- cbuf: [0:16)=b1@w2l  [16:32)=b1@w2r  [32:48)=v=fc1w@fc2w  [48]=c
__global__ void precomp_consts(const float* __restrict__ b1,
    const float* __restrict__ w2l, const float* __restrict__ w2r,
    const float* __restrict__ fc1w, const float* __restrict__ fc1b,
    const float* __restrict__ fc2w, const float* __restrict__ fc2b,
    float* __restrict__ cbuf)
{
    const int j = threadIdx.x;
    if (j < 16) {
        float a = 0.f;
        for (int m = 0; m < 64; ++m) a = fmaf(b1[m], w2l[m * 16 + j], a);
        cbuf[j] = a;
    } else if (j < 32) {
        const int jj = j - 16;
        float a = 0.f;
        for (int m = 0; m < 64; ++m) a = fmaf(b1[m], w2r[m * 16 + jj], a);
        cbuf[j] = a;
    } else if (j < 48) {
        const int k = j - 32;
        float a = 0.f;
        for (int m = 0; m < 8; ++m) a = fmaf(fc1w[k * 8 + m], fc2w[m], a);
        cbuf[j] = a;
    } else if (j == 48) {
        float a = fc2b[0];
        for (int m = 0; m < 8; ++m) a = fmaf(fc1b[m], fc2w[m], a);
        cbuf[48] = a;
    }
}

// ---- MFMA GEMM: y = x @ A (bf16 3-term split).
//      p (cols 0..31) -> int8 + per-row scale;  q (cols 32..63) -> fp16
#define LDST 136
__global__ __launch_bounds__(256) void gemm_mfma(const float* __restrict__ x,
    const unsigned short* __restrict__ ATh, const unsigned short* __restrict__ ATl,
    signed char* __restrict__ p8, float* __restrict__ pscale,
    __half* __restrict__ qh)
{
    __shared__ unsigned short sAh[64 * LDST];
    __shared__ unsigned short sAl[64 * LDST];
    const int tid = threadIdx.x;
    for (int i = tid; i < 1024; i += 256) {
        const int row = i >> 4, ch = i & 15;
        const uint4 vh = *(const uint4*)(ATh + row * 128 + ch * 8);
        const uint4 vl = *(const uint4*)(ATl + row * 128 + ch * 8);
        *(uint4*)(sAh + row * LDST + ch * 8) = vh;
        *(uint4*)(sAl + row * LDST + ch * 8) = vl;
    }
    __syncthreads();

    const int wave = tid >> 6;
    const int lane = tid & 63;
    const int lr = lane & 15;
    const int lg = lane >> 4;

    bf16x8 bh[4][4], bl[4][4];
#pragma unroll
    for (int ct = 0; ct < 4; ++ct) {
        const int col = ct * 16 + lr;
#pragma unroll
        for (int ks = 0; ks < 4; ++ks) {
            const int k0 = ks * 32 + lg * 8;
            bh[ct][ks] = *(const bf16x8*)(sAh + col * LDST + k0);
            bl[ct][ks] = *(const bf16x8*)(sAl + col * LDST + k0);
        }
    }

    const int tilebase = blockIdx.x * 64;
    const int xrowidx = tilebase + wave * 16 + lr;
    const float* xrow = x + (size_t)(xrowidx < NN ? xrowidx : NN - 1) * 128;

    f32x4 acc[4] = {f32x4{0,0,0,0}, f32x4{0,0,0,0}, f32x4{0,0,0,0}, f32x4{0,0,0,0}};
#pragma unroll
    for (int ks = 0; ks < 4; ++ks) {
        const int k0 = ks * 32 + lg * 8;
        const float4 v0 = *(const float4*)(xrow + k0);
        const float4 v1 = *(const float4*)(xrow + k0 + 4);
        const float vv[8] = {v0.x, v0.y, v0.z, v0.w, v1.x, v1.y, v1.z, v1.w};
        bf16x8 xh, xl;
#pragma unroll
        for (int j = 0; j < 8; ++j) {
            const unsigned short h = f2bf(vv[j]);
            xh[j] = (short)h;
            xl[j] = (short)f2bf(vv[j] - bf2f(h));
        }
#pragma unroll
        for (int ct = 0; ct < 4; ++ct) {
            acc[ct] = __builtin_amdgcn_mfma_f32_16x16x32_bf16(xh, bh[ct][ks], acc[ct], 0, 0, 0);
            acc[ct] = __builtin_amdgcn_mfma_f32_16x16x32_bf16(xh, bl[ct][ks], acc[ct], 0, 0, 0);
            acc[ct] = __builtin_amdgcn_mfma_f32_16x16x32_bf16(xl, bh[ct][ks], acc[ct], 0, 0, 0);
        }
    }

    // D layout: row = tilebase + wave*16 + lg*4 + rg; col = ct*16 + lr
#pragma unroll
    for (int rg = 0; rg < 4; ++rg) {
        float m = fmaxf(fabsf(acc[0][rg]), fabsf(acc[1][rg]));
#pragma unroll
        for (int d = 1; d < 16; d <<= 1) m = fmaxf(m, __shfl_xor(m, d, 64));
        m = fmaxf(m, 1e-20f);
        const float scl = m * (1.0f / 127.0f);
        const float inv = 127.0f / m;
        const int nrow = tilebase + wave * 16 + lg * 4 + rg;
        if (nrow < NN) {
            const int q0 = __float2int_rn(acc[0][rg] * inv);
            const int q1 = __float2int_rn(acc[1][rg] * inv);
            p8[(size_t)nrow * 32 + lr]      = (signed char)q0;
            p8[(size_t)nrow * 32 + 16 + lr] = (signed char)q1;
            if (lr == 0) pscale[nrow] = scl;
            qh[(size_t)nrow * 32 + lr]      = __float2half(acc[2][rg]);
            qh[(size_t)nrow * 32 + 16 + lr] = __float2half(acc[3][rg]);
        }
    }
}

// ============ bucketed CSR build ============
// mat layout: [bucket][ablock]  (contiguous per-bucket for parallel scan)
__global__ __launch_bounds__(256) void partA_count(const int* __restrict__ dst,
    int* __restrict__ mat)
{
    __shared__ int h[NB];
    for (int i = threadIdx.x; i < NB; i += 256) h[i] = 0;
    __syncthreads();
    const int a = blockIdx.x;
    const int beg = a * EPB;
    const int end = (beg + EPB < NE) ? beg + EPB : NE;
    for (int e = beg + threadIdx.x; e < end; e += 256)
        atomicAdd(&h[dst[e] >> BSH], 1);
    __syncthreads();
    for (int i = threadIdx.x; i < NB; i += 256) mat[(size_t)i * ABLK + a] = h[i];
}

__global__ __launch_bounds__(256) void scan_cols(int* __restrict__ mat,
    int* __restrict__ tot)
{
    const int b = blockIdx.x * 256 + threadIdx.x;
    if (b >= NB) return;
    int* col = mat + (size_t)b * ABLK;
    int run = 0;
    for (int a = 0; a < ABLK; ++a) { const int t = col[a]; col[a] = run; run += t; }
    tot[b] = run;
}

__global__ void scan_tot(const int* __restrict__ tot, int* __restrict__ bbase)
{
    if (threadIdx.x == 0) {
        int acc = 0;
        for (int i = 0; i < NB; ++i) { bbase[i] = acc; acc += tot[i]; }
        bbase[NB] = acc;   // == NE
    }
}

// packed entry: (src << BSH) | local_dst
__global__ __launch_bounds__(256) void partA_scatter(const int* __restrict__ src,
    const int* __restrict__ dst, const int* __restrict__ mat,
    const int* __restrict__ bbase, unsigned* __restrict__ part)
{
    __shared__ int cur[NB];
    const int a = blockIdx.x;
    for (int i = threadIdx.x; i < NB; i += 256)
        cur[i] = mat[(size_t)i * ABLK + a] + bbase[i];
    __syncthreads();
    const int beg = a * EPB;
    const int end = (beg + EPB < NE) ? beg + EPB : NE;
    for (int e = beg + threadIdx.x; e < end; e += 256) {
        const int s = src[e], d = dst[e];
        const int pos = atomicAdd(&cur[d >> BSH], 1);
        part[pos] = ((unsigned)s << BSH) | (unsigned)(d & (BKN - 1));
    }
}

__global__ __launch_bounds__(512) void partB_build(const unsigned* __restrict__ part,
    const int* __restrict__ bbase, int* __restrict__ rowptr, int* __restrict__ cols)
{
    __shared__ int h[BKN];
    __shared__ int cur[BKN];
    const int b = blockIdx.x;
    const int beg = bbase[b], end = bbase[b + 1];
    h[threadIdx.x] = 0;
    __syncthreads();
    for (int e = beg + threadIdx.x; e < end; e += 512)
        atomicAdd(&h[part[e] & (BKN - 1u)], 1);
    __syncthreads();
    const int v = h[threadIdx.x];
    for (int off = 1; off < BKN; off <<= 1) {
        const int t = (threadIdx.x >= off) ? h[threadIdx.x - off] : 0;
        __syncthreads();
        h[threadIdx.x] += t;
        __syncthreads();
    }
    const int excl = h[threadIdx.x] - v;
    cur[threadIdx.x] = excl;
    const int node = b * BKN + threadIdx.x;
    if (node < NN) rowptr[node] = beg + excl;
    if (b == NB - 1 && threadIdx.x == 0) rowptr[NN] = NE;
    __syncthreads();
    for (int e = beg + threadIdx.x; e < end; e += 512) {
        const unsigned w = part[e];
        const int pos = atomicAdd(&cur[w & (BKN - 1u)], 1);
        cols[beg + pos] = (int)(w >> BSH);
    }
}

// ============ aggregation via CSR (vectorized dword gathers) ============
// layer 1: 32 lanes per node = 4 edge-slots x 8 dword-lanes.
// lane k of slot es loads dword k (4 int8 feats) of edge (j+es)'s p8 row.
__global__ __launch_bounds__(256) void agg1_csr(const int* __restrict__ rowptr,
    const int* __restrict__ cols, const signed char* __restrict__ p8,
    const float* __restrict__ pscale, const __half* __restrict__ qh,
    const float* __restrict__ cbuf, __half* __restrict__ g, __half* __restrict__ r)
{
    const int node = blockIdx.x * 8 + (threadIdx.x >> 5);
    if (node >= NN) return;
    const int lane = threadIdx.x & 31;
    const int es = lane >> 3;      // edge slot 0..3
    const int k  = lane & 7;       // dword index 0..7
    const int beg = rowptr[node], end = rowptr[node + 1];
    const unsigned* p32 = (const unsigned*)p8;
    float a0 = 0.f, a1 = 0.f, a2 = 0.f, a3 = 0.f;
#pragma unroll 2
    for (int j = beg; j < end; j += 4) {
        const int jj = j + es;
        const int s = cols[(jj < end) ? jj : (end - 1)];
        const float scl = (jj < end) ? pscale[s] : 0.f;
        const unsigned w = p32[(size_t)s * 8 + k];
        a0 = fmaf((float)(signed char)(w & 0xffu), scl, a0);
        a1 = fmaf((float)(signed char)((w >> 8) & 0xffu), scl, a1);
        a2 = fmaf((float)(signed char)((w >> 16) & 0xffu), scl, a2);
        a3 = fmaf((float)(signed char)(w >> 24), scl, a3);
    }
    a0 += __shfl_xor(a0, 8, 64);  a0 += __shfl_xor(a0, 16, 64);
    a1 += __shfl_xor(a1, 8, 64);  a1 += __shfl_xor(a1, 16, 64);
    a2 += __shfl_xor(a2, 8, 64);  a2 += __shfl_xor(a2, 16, 64);
    a3 += __shfl_xor(a3, 8, 64);  a3 += __shfl_xor(a3, 16, 64);
    if (es == 0) {
        // lane k holds features 4k..4k+3
        const float dg = (float)(end - beg);
        const float inv = 1.0f / fmaxf(dg, 1.0f);
        const uint2 qw = *(const uint2*)(qh + (size_t)node * 32 + 4 * k);
        const float2 q01 = unpackh2(qw.x), q23 = unpackh2(qw.y);
        const float4 cb = *(const float4*)(cbuf + 4 * k);
        const float v0 = fmaf(a0, inv, q01.x + cb.x);
        const float v1 = fmaf(a1, inv, q01.y + cb.y);
        const float v2 = fmaf(a2, inv, q23.x + cb.z);
        const float v3 = fmaf(a3, inv, q23.y + cb.w);
        uint2 ow;
        ow.x = __builtin_bit_cast(unsigned, __floats2half2_rn(v0, v1));
        ow.y = __builtin_bit_cast(unsigned, __floats2half2_rn(v2, v3));
        if (k < 4) *(uint2*)(g + (size_t)node * 16 + 4 * k) = ow;
        else       *(uint2*)(r + (size_t)node * 16 + 4 * (k - 4)) = ow;
    }
}

// layer 2: 32 lanes per node = 4 edge-slots x 8 dword-lanes (2 fp16 feats per lane)
__global__ __launch_bounds__(256) void agg2_csr(const int* __restrict__ rowptr,
    const int* __restrict__ cols, const __half* __restrict__ g,
    const __half* __restrict__ r, const float* __restrict__ b2,
    __half* __restrict__ h2)
{
    const int node = blockIdx.x * 8 + (threadIdx.x >> 5);
    if (node >= NN) return;
    const int lane = threadIdx.x & 31;
    const int es = lane >> 3;
    const int k  = lane & 7;
    const int beg = rowptr[node], end = rowptr[node + 1];
    const unsigned* g32 = (const unsigned*)g;
    float a0 = 0.f, a1 = 0.f;
#pragma unroll 2
    for (int j = beg; j < end; j += 4) {
        const int jj = j + es;
        const int s = cols[(jj < end) ? jj : (end - 1)];
        const float m = (jj < end) ? 1.0f : 0.0f;
        const float2 v = unpackh2(g32[(size_t)s * 8 + k]);
        a0 = fmaf(v.x, m, a0);
        a1 = fmaf(v.y, m, a1);
    }
    a0 += __shfl_xor(a0, 8, 64);  a0 += __shfl_xor(a0, 16, 64);
    a1 += __shfl_xor(a1, 8, 64);  a1 += __shfl_xor(a1, 16, 64);
    if (es == 0) {
        // lane k holds features 2k, 2k+1
        const float dg = (float)(end - beg);
        const float inv = 1.0f / fmaxf(dg, 1.0f);
        const float2 rv = unpackh2(((const unsigned*)r)[(size_t)node * 8 + k]);
        const float2 bb = *(const float2*)(b2 + 2 * k);
        const float v0 = fmaf(a0, inv, rv.x + bb.x);
        const float v1 = fmaf(a1, inv, rv.y + bb.y);
        ((unsigned*)h2)[(size_t)node * 8 + k] =
            __builtin_bit_cast(unsigned, __floats2half2_rn(v0, v1));
    }
}

// ---- out = sigmoid( sum_k h2[s][k]*h2[d][k]*v[k] + c )
__global__ __launch_bounds__(256) void edge_mlp(const int* __restrict__ src,
    const int* __restrict__ dst, const __half* __restrict__ h2,
    const float* __restrict__ cbuf, float* __restrict__ out)
{
    __shared__ float sv[17];
    if (threadIdx.x < 16) sv[threadIdx.x] = cbuf[32 + threadIdx.x];
    if (threadIdx.x == 16) sv[16] = cbuf[48];
    __syncthreads();
    const int e = blockIdx.x * 256 + threadIdx.x;
    if (e >= NE) return;
    const int s = src[e], d = dst[e];
    const uint4* hs = (const uint4*)(h2 + (size_t)s * 16);
    const uint4* hd = (const uint4*)(h2 + (size_t)d * 16);
    float acc = sv[16];
    const uint4 a0 = hs[0], a1 = hs[1];
    const uint4 b0 = hd[0], b1 = hd[1];
    const unsigned aw[8] = {a0.x, a0.y, a0.z, a0.w, a1.x, a1.y, a1.z, a1.w};
    const unsigned bw[8] = {b0.x, b0.y, b0.z, b0.w, b1.x, b1.y, b1.z, b1.w};
#pragma unroll
    for (int qq = 0; qq < 8; ++qq) {
        const float2 a = unpackh2(aw[qq]);
        const float2 b = unpackh2(bw[qq]);
        acc = fmaf(a.x * b.x, sv[qq * 2 + 0], acc);
        acc = fmaf(a.y * b.y, sv[qq * 2 + 1], acc);
    }
    out[e] = 1.0f / (1.0f + __expf(-acc));
}

extern "C" void kernel_launch(void* const* d_in, const int* in_sizes, int n_in,
                              void* d_out, int out_size, void* d_ws, size_t ws_size,
                              hipStream_t stream)
{
    const float* x    = (const float*)d_in[0];
    const int*   ei   = (const int*)d_in[1];
    const float* w1l  = (const float*)d_in[2];
    const float* w1r  = (const float*)d_in[3];
    const float* b1   = (const float*)d_in[4];
    const float* w2l  = (const float*)d_in[5];
    const float* w2r  = (const float*)d_in[6];
    const float* b2   = (const float*)d_in[7];
    const float* fc1w = (const float*)d_in[8];
    const float* fc1b = (const float*)d_in[9];
    const float* fc2w = (const float*)d_in[10];
    const float* fc2b = (const float*)d_in[11];
    float* out = (float*)d_out;

    const int* src = ei;
    const int* dst = ei + NE;

    // workspace layout (int units)
    int* W = (int*)d_ws;
    size_t o = 0;
#define ALIGN16() o = (o + 15) & ~(size_t)15
    int* mat    = W + o; o += (size_t)NB * ABLK; ALIGN16();
    int* tot    = W + o; o += NB;                ALIGN16();
    int* bbase  = W + o; o += NB + 1;            ALIGN16();
    int* rowptr = W + o; o += NN + 1;            ALIGN16();
    unsigned* part = (unsigned*)(W + o); o += NE; ALIGN16();
    int* cols   = W + o; o += NE;                ALIGN16();
    float* A    = (float*)(W + o); o += 8192;    ALIGN16();
    unsigned short* ATh = (unsigned short*)(W + o); o += 4096; ALIGN16();
    unsigned short* ATl = (unsigned short*)(W + o); o += 4096; ALIGN16();
    float* cbuf = (float*)(W + o); o += 64;      ALIGN16();
    signed char* p8 = (signed char*)(W + o); o += (size_t)NN * 8;  ALIGN16();
    float* pscale   = (float*)(W + o); o += NN;  ALIGN16();
    __half* qh  = (__half*)(W + o); o += (size_t)NN * 16; ALIGN16();
    __half* g   = (__half*)(W + o); o += (size_t)NN * 8;  ALIGN16();
    __half* r   = (__half*)(W + o); o += (size_t)NN * 8;  ALIGN16();
    __half* h2  = (__half*)(W + o); o += (size_t)NN * 8;  ALIGN16();

    precomp_A<<<128, 64, 0, stream>>>(w1l, w1r, w2l, w2r, A);
    convA<<<32, 256, 0, stream>>>(A, ATh, ATl);
    precomp_consts<<<1, 64, 0, stream>>>(b1, w2l, w2r, fc1w, fc1b, fc2w, fc2b, cbuf);

    // bucketed CSR build (parallel scan)
    partA_count<<<ABLK, 256, 0, stream>>>(dst, mat);
    scan_cols<<<(NB + 255) / 256, 256, 0, stream>>>(mat, tot);
    scan_tot<<<1, 64, 0, stream>>>(tot, bbase);
    partA_scatter<<<ABLK, 256, 0, stream>>>(src, dst, mat, bbase, part);
    partB_build<<<NB, 512, 0, stream>>>(part, bbase, rowptr, cols);

    // dense projection (MFMA, int8 payload epilogue)
    gemm_mfma<<<(NN + 63) / 64, 256, 0, stream>>>(x, ATh, ATl, p8, pscale, qh);

    // aggregations (vectorized dword gathers, 4 edge-slots per node-group)
    agg1_csr<<<(NN + 7) / 8, 256, 0, stream>>>(rowptr, cols, p8, pscale, qh, cbuf, g, r);
    agg2_csr<<<(NN + 7) / 8, 256, 0, stream>>>(rowptr, cols, g, r, b2, h2);

    // head
    edge_mlp<<<NE / 256, 256, 0, stream>>>(src, dst, h2, cbuf, out);
}